// Round 2
// baseline (546.082 us; speedup 1.0000x reference)
//
#include <hip/hip_runtime.h>
#include <cstdint>
#include <cstddef>

// Out[M][N] = X[M][K] @ W[N][K]^T + bias[N].  f32 storage, bf16 MFMA compute.
#define M_DIM 8192
#define N_DIM 4096
#define K_DIM 4096
#define BM 128
#define BN 128
// BK = 64 as two 128x32 bf16 panels (64B rows) in LDS.

typedef __bf16 bf16x8 __attribute__((ext_vector_type(8)));
typedef float  f32x4  __attribute__((ext_vector_type(4)));
typedef unsigned short u16x4 __attribute__((ext_vector_type(4)));

__device__ __forceinline__ unsigned short f32_to_bf16(float f) {
    unsigned int v = __builtin_bit_cast(unsigned int, f);
    v += 0x7FFFu + ((v >> 16) & 1u);   // round-to-nearest-even
    return (unsigned short)(v >> 16);
}

__device__ __forceinline__ void load16_lds(const void* g, void* l) {
    __builtin_amdgcn_global_load_lds(
        (__attribute__((address_space(1))) void*)(g),
        (__attribute__((address_space(3))) void*)(l),
        16, 0, 0);
}

// ---------- pre-pass: f32 -> bf16 (RNE), vectorized ----------
__global__ void cvt_f32_to_bf16(const float* __restrict__ src,
                                unsigned short* __restrict__ dst, int n4) {
    int i = blockIdx.x * blockDim.x + threadIdx.x;
    const int stride = gridDim.x * blockDim.x;
    for (; i < n4; i += stride) {
        f32x4 v = *(const f32x4*)(src + (size_t)i * 4);
        u16x4 o;
        o.x = f32_to_bf16(v.x); o.y = f32_to_bf16(v.y);
        o.z = f32_to_bf16(v.z); o.w = f32_to_bf16(v.w);
        *(u16x4*)(dst + (size_t)i * 4) = o;
    }
}

// ---------- main GEMM: bf16 inputs from ws, async LDS staging ----------
__global__ __launch_bounds__(256, 3) void gemm_bt_async(
    const unsigned short* __restrict__ X,    // [M][K] bf16 (ws)
    const unsigned short* __restrict__ W,    // [N][K] bf16 (ws)
    const float* __restrict__ Bias,          // [N] f32
    float* __restrict__ Out)                 // [M][N] f32
{
    __shared__ alignas(16) unsigned short sA[2][BM][32];
    __shared__ alignas(16) unsigned short sB[2][BN][32];

    const int tid  = threadIdx.x;
    const int wave = tid >> 6;
    const int lane = tid & 63;
    const int tileM = blockIdx.x * BM;
    const int tileN = blockIdx.y * BN;

    // staging: lane l -> row l>>2, col8 (l&3)*8 within a 16-row slab
    const int srow = wave * 16 + (lane >> 2);
    const int scol = (lane & 3) * 8;
    const unsigned short* gA = X + (size_t)(tileM + srow) * K_DIM + scol;
    const unsigned short* gB = W + (size_t)(tileN + srow) * K_DIM + scol;

    const int fr = lane & 15;   // m (A) / n (B) within 16-tile
    const int fq = lane >> 4;   // quad: k = fq*8 + j
    const int wm = (wave >> 1) * 64;
    const int wn = (wave & 1) * 64;

    f32x4 acc[4][4];
    #pragma unroll
    for (int i = 0; i < 4; ++i)
        #pragma unroll
        for (int j = 0; j < 4; ++j)
            acc[i][j] = f32x4{0.f, 0.f, 0.f, 0.f};

    for (int k0 = 0; k0 < K_DIM; k0 += 64) {
        __syncthreads();
        #pragma unroll
        for (int p = 0; p < 2; ++p) {
            #pragma unroll
            for (int ks = 0; ks < 2; ++ks) {
                load16_lds(gA + (size_t)p * 64 * K_DIM + k0 + ks * 32,
                           &sA[ks][p * 64 + wave * 16][0]);
                load16_lds(gB + (size_t)p * 64 * K_DIM + k0 + ks * 32,
                           &sB[ks][p * 64 + wave * 16][0]);
            }
        }
        __syncthreads();

        #pragma unroll
        for (int ks = 0; ks < 2; ++ks) {
            bf16x8 af[4], bfr[4];
            #pragma unroll
            for (int i = 0; i < 4; ++i) {
                af[i]  = *(const bf16x8*)&sA[ks][wm + i * 16 + fr][fq * 8];
                bfr[i] = *(const bf16x8*)&sB[ks][wn + i * 16 + fr][fq * 8];
            }
            #pragma unroll
            for (int i = 0; i < 4; ++i)
                #pragma unroll
                for (int j = 0; j < 4; ++j)
                    acc[i][j] = __builtin_amdgcn_mfma_f32_16x16x32_bf16(
                        af[i], bfr[j], acc[i][j], 0, 0, 0);
        }
    }

    #pragma unroll
    for (int j = 0; j < 4; ++j) {
        const int col = tileN + wn + j * 16 + fr;
        const float bv = Bias[col];
        #pragma unroll
        for (int i = 0; i < 4; ++i) {
            const int rowb = tileM + wm + i * 16 + fq * 4;
            f32x4 v = acc[i][j];
            #pragma unroll
            for (int r = 0; r < 4; ++r)
                Out[(size_t)(rowb + r) * N_DIM + col] = v[r] + bv;
        }
    }
}

// ---------- fallback GEMM (ws too small): f32 load + cvt during staging ----
__global__ __launch_bounds__(256, 3) void gemm_bt_reg(
    const float* __restrict__ X,    // [M][K] f32
    const float* __restrict__ W,    // [N][K] f32
    const float* __restrict__ Bias,
    float* __restrict__ Out)
{
    __shared__ alignas(16) unsigned short sA[2][BM][32];
    __shared__ alignas(16) unsigned short sB[2][BN][32];

    const int tid  = threadIdx.x;
    const int wave = tid >> 6;
    const int lane = tid & 63;
    const int tileM = blockIdx.x * BM;
    const int tileN = blockIdx.y * BN;

    const int fr = lane & 15;
    const int fq = lane >> 4;
    const int wm = (wave >> 1) * 64;
    const int wn = (wave & 1) * 64;

    f32x4 acc[4][4];
    #pragma unroll
    for (int i = 0; i < 4; ++i)
        #pragma unroll
        for (int j = 0; j < 4; ++j)
            acc[i][j] = f32x4{0.f, 0.f, 0.f, 0.f};

    for (int k0 = 0; k0 < K_DIM; k0 += 64) {
        __syncthreads();
        // stage A and B: per panel ks, 128 rows x 32 f32; thread -> 4 float4
        #pragma unroll
        for (int ks = 0; ks < 2; ++ks) {
            #pragma unroll
            for (int jj = 0; jj < 4; ++jj) {
                const int f   = tid + jj * 256;   // 0..1023
                const int row = f >> 3;
                const int c4  = (f & 7) * 4;
                f32x4 va = *(const f32x4*)(X + (size_t)(tileM + row) * K_DIM + k0 + ks * 32 + c4);
                f32x4 vb = *(const f32x4*)(W + (size_t)(tileN + row) * K_DIM + k0 + ks * 32 + c4);
                u16x4 oa, ob;
                oa.x = f32_to_bf16(va.x); oa.y = f32_to_bf16(va.y);
                oa.z = f32_to_bf16(va.z); oa.w = f32_to_bf16(va.w);
                ob.x = f32_to_bf16(vb.x); ob.y = f32_to_bf16(vb.y);
                ob.z = f32_to_bf16(vb.z); ob.w = f32_to_bf16(vb.w);
                *(u16x4*)&sA[ks][row][c4] = oa;
                *(u16x4*)&sB[ks][row][c4] = ob;
            }
        }
        __syncthreads();

        #pragma unroll
        for (int ks = 0; ks < 2; ++ks) {
            bf16x8 af[4], bfr[4];
            #pragma unroll
            for (int i = 0; i < 4; ++i) {
                af[i]  = *(const bf16x8*)&sA[ks][wm + i * 16 + fr][fq * 8];
                bfr[i] = *(const bf16x8*)&sB[ks][wn + i * 16 + fr][fq * 8];
            }
            #pragma unroll
            for (int i = 0; i < 4; ++i)
                #pragma unroll
                for (int j = 0; j < 4; ++j)
                    acc[i][j] = __builtin_amdgcn_mfma_f32_16x16x32_bf16(
                        af[i], bfr[j], acc[i][j], 0, 0, 0);
        }
    }

    #pragma unroll
    for (int j = 0; j < 4; ++j) {
        const int col = tileN + wn + j * 16 + fr;
        const float bv = Bias[col];
        #pragma unroll
        for (int i = 0; i < 4; ++i) {
            const int rowb = tileM + wm + i * 16 + fq * 4;
            f32x4 v = acc[i][j];
            #pragma unroll
            for (int r = 0; r < 4; ++r)
                Out[(size_t)(rowb + r) * N_DIM + col] = v[r] + bv;
        }
    }
}

extern "C" void kernel_launch(void* const* d_in, const int* in_sizes, int n_in,
                              void* d_out, int out_size, void* d_ws, size_t ws_size,
                              hipStream_t stream) {
    const float* X    = (const float*)d_in[0];  // [8192][4096]
    const float* W    = (const float*)d_in[1];  // [4096][4096]
    const float* Bias = (const float*)d_in[2];  // [4096]
    float* Out = (float*)d_out;

    const size_t nX = (size_t)M_DIM * K_DIM;          // 33554432
    const size_t nW = (size_t)N_DIM * K_DIM;          // 16777216
    const size_t need = (nX + nW) * sizeof(unsigned short);  // ~96 MB

    dim3 grid(M_DIM / BM, N_DIM / BN);

    if (ws_size >= need) {
        unsigned short* wsX = (unsigned short*)d_ws;
        unsigned short* wsW = wsX + nX;
        cvt_f32_to_bf16<<<2048, 256, 0, stream>>>(X, wsX, (int)(nX / 4));
        cvt_f32_to_bf16<<<1024, 256, 0, stream>>>(W, wsW, (int)(nW / 4));
        gemm_bt_async<<<grid, dim3(256), 0, stream>>>(wsX, wsW, Bias, Out);
    } else {
        gemm_bt_reg<<<grid, dim3(256), 0, stream>>>(X, W, Bias, Out);
    }
}